// Round 2
// baseline (206.949 us; speedup 1.0000x reference)
//
#include <hip/hip_runtime.h>
#include <stdint.h>

#define Hdim 112
#define Wdim 112
#define CIN  128
#define COUT 128
#define NB   32
#define HW   (Hdim*Wdim)   // 12544

// ws layout:
//   Wp  : uint4[COUT*9]   @ 0        (18432 B)  packed weight sign bits
//   cw  : int [COUT*9]    @ 18432    (4608 B)   128 - 2*popc(w_tap)
//   pkx : uint4[NB*HW]    @ 23040    (6.4 MB)   packed activation sign bits

__global__ void pack_w_kernel(const float* __restrict__ W,
                              uint4* __restrict__ Wp, int* __restrict__ cw) {
    int t = blockIdx.x * blockDim.x + threadIdx.x;
    if (t >= COUT * 9) return;
    int co = t / 9, tap = t % 9;
    uint32_t m0 = 0, m1 = 0, m2 = 0, m3 = 0;
    const float* wp = W + (size_t)co * CIN * 9 + tap;
    #pragma unroll
    for (int c = 0; c < CIN; c++) {
        uint32_t bit = (__float_as_uint(wp[(size_t)c * 9]) >> 31);
        if (c < 32)       m0 |= bit << (c & 31);
        else if (c < 64)  m1 |= bit << (c & 31);
        else if (c < 96)  m2 |= bit << (c & 31);
        else              m3 |= bit << (c & 31);
    }
    Wp[t] = make_uint4(m0, m1, m2, m3);
    cw[t] = CIN - 2 * (__popc(m0) + __popc(m1) + __popc(m2) + __popc(m3));
}

// each thread packs 2 consecutive pixels across all 128 channels
__global__ __launch_bounds__(256) void pack_x_kernel(const float* __restrict__ x,
                                                     uint4* __restrict__ pkx) {
    int gid = blockIdx.x * blockDim.x + threadIdx.x;   // 0..200703
    int n = gid / (HW / 2);
    int p = (gid - n * (HW / 2)) * 2;
    const float* xp = x + (size_t)n * CIN * HW + p;
    uint32_t a0=0,a1=0,a2=0,a3=0, b0=0,b1=0,b2=0,b3=0;
    #pragma unroll
    for (int c = 0; c < CIN; c++) {
        float2 v = *reinterpret_cast<const float2*>(xp + (size_t)c * HW);
        uint32_t ba = __float_as_uint(v.x) >> 31;
        uint32_t bb = __float_as_uint(v.y) >> 31;
        if (c < 32)      { a0 |= ba << (c & 31); b0 |= bb << (c & 31); }
        else if (c < 64) { a1 |= ba << (c & 31); b1 |= bb << (c & 31); }
        else if (c < 96) { a2 |= ba << (c & 31); b2 |= bb << (c & 31); }
        else             { a3 |= ba << (c & 31); b3 |= bb << (c & 31); }
    }
    pkx[(size_t)n * HW + p]     = make_uint4(a0, a1, a2, a3);
    pkx[(size_t)n * HW + p + 1] = make_uint4(b0, b1, b2, b3);
}

// main conv: block = 16x16 pixel tile; window tile staged in LDS once;
// each block computes 64 consecutive c_out. OOB taps are zero bits,
// corrected by border_fix_kernel.
__global__ __launch_bounds__(256) void binconv_kernel(
    const uint4* __restrict__ pkx, const uint4* __restrict__ Wp,
    const float* __restrict__ bias, float* __restrict__ out) {
    __shared__ uint4 tile[18 * 18];

    int tx = threadIdx.x & 15;
    int ty = threadIdx.x >> 4;
    int w0 = blockIdx.x * 16;
    int h0 = blockIdx.y * 16;
    int bz = blockIdx.z;
    int n   = bz >> 1;
    int co0 = (bz & 1) * 64;

    const uint4* px = pkx + (size_t)n * HW;

    // cooperative stage of 18x18 window (zeros for out-of-image)
    for (int i = threadIdx.x; i < 324; i += 256) {
        int r = i / 18, c = i - r * 18;
        int hh = h0 - 1 + r, ww = w0 - 1 + c;
        bool valid = (hh >= 0) & (hh < Hdim) & (ww >= 0) & (ww < Wdim);
        uint4 val = make_uint4(0u, 0u, 0u, 0u);
        if (valid) val = px[hh * Wdim + ww];
        tile[i] = val;
    }
    __syncthreads();

    // pull this thread's 3x3 window into registers (one-time LDS reads)
    uint4 xw[3][3];
    #pragma unroll
    for (int dy = 0; dy < 3; dy++)
        #pragma unroll
        for (int dx = 0; dx < 3; dx++)
            xw[dy][dx] = tile[(ty + dy) * 18 + (tx + dx)];

    int h = h0 + ty, w = w0 + tx;
    const float* bp = bias + co0;
    const uint4* wv = Wp + co0 * 9;
    float* obase = out + (size_t)(n * COUT + co0) * HW;
    unsigned off = (unsigned)(h * Wdim + w);

    #pragma unroll 2
    for (int co = 0; co < 64; co++) {
        int P0 = 0, P1 = 0, P2 = 0, P3 = 0;
        #pragma unroll
        for (int t = 0; t < 9; t++) {
            uint4 wt = wv[co * 9 + t];
            uint4 a  = xw[t / 3][t % 3];
            P0 += __popc(a.x ^ wt.x);
            P1 += __popc(a.y ^ wt.y);
            P2 += __popc(a.z ^ wt.z);
            P3 += __popc(a.w ^ wt.w);
        }
        float fb = 1152.0f + bp[co];
        obase[off + (unsigned)co * HW] = fmaf(-2.0f, (float)(P0 + P1 + P2 + P3), fb);
    }
}

// subtract the spurious zero-pad contribution on the 444 border pixels/image
__global__ void border_fix_kernel(const int* __restrict__ cw, float* __restrict__ out) {
    const int BP = 444;
    int t = blockIdx.x * blockDim.x + threadIdx.x;
    int total = NB * COUT * BP;
    if (t >= total) return;
    int bp = t % BP;
    int rc = t / BP;
    int co = rc % COUT;
    int n  = rc / COUT;
    int h, w;
    if (bp < 112)      { h = 0;   w = bp; }
    else if (bp < 224) { h = 111; w = bp - 112; }
    else { int r = bp - 224; h = (r >> 1) + 1; w = (r & 1) ? 111 : 0; }
    const int* c9 = cw + co * 9;
    int corr = 0;
    #pragma unroll
    for (int ky = 0; ky < 3; ky++) {
        #pragma unroll
        for (int kx = 0; kx < 3; kx++) {
            int hh = h + ky - 1, ww = w + kx - 1;
            if ((hh < 0) | (hh >= Hdim) | (ww < 0) | (ww >= Wdim))
                corr += c9[ky * 3 + kx];
        }
    }
    size_t idx = ((size_t)(n * COUT + co) * HW) + (size_t)h * Wdim + w;
    out[idx] -= (float)corr;
}

extern "C" void kernel_launch(void* const* d_in, const int* in_sizes, int n_in,
                              void* d_out, int out_size, void* d_ws, size_t ws_size,
                              hipStream_t stream) {
    const float* x = (const float*)d_in[0];
    const float* W = (const float*)d_in[1];
    const float* b = (const float*)d_in[2];
    float* out = (float*)d_out;
    char* ws = (char*)d_ws;
    uint4* Wp  = (uint4*)ws;
    int*   cw  = (int*)(ws + 18432);
    uint4* pkx = (uint4*)(ws + 23040);

    pack_w_kernel<<<dim3((COUT * 9 + 255) / 256), dim3(256), 0, stream>>>(W, Wp, cw);
    pack_x_kernel<<<dim3(NB * HW / 2 / 256), dim3(256), 0, stream>>>(x, pkx);
    binconv_kernel<<<dim3(7, 7, NB * 2), dim3(256), 0, stream>>>(pkx, Wp, b, out);
    border_fix_kernel<<<dim3((NB * COUT * 444 + 255) / 256), dim3(256), 0, stream>>>(cw, out);
}

// Round 3
// 193.936 us; speedup vs baseline: 1.0671x; 1.0671x over previous
//
#include <hip/hip_runtime.h>
#include <stdint.h>

#define Hdim 112
#define Wdim 112
#define CIN  128
#define COUT 128
#define NB   32
#define HW   (Hdim*Wdim)   // 12544

// ws layout:
//   Wp  : uint4[COUT*9]   @ 0        (18432 B)  packed weight sign bits
//   cw  : int [COUT*9]    @ 18432    (4608 B)   128 - 2*popc(w_tap)
//   pkx : uint4[NB*HW]    @ 23040    (6.4 MB)   packed activation sign bits

__global__ void pack_w_kernel(const float* __restrict__ W,
                              uint4* __restrict__ Wp, int* __restrict__ cw) {
    int t = blockIdx.x * blockDim.x + threadIdx.x;
    if (t >= COUT * 9) return;
    int co = t / 9, tap = t % 9;
    uint32_t m0 = 0, m1 = 0, m2 = 0, m3 = 0;
    const float* wp = W + (size_t)co * CIN * 9 + tap;
    #pragma unroll
    for (int c = 0; c < CIN; c++) {
        uint32_t bit = (__float_as_uint(wp[(size_t)c * 9]) >> 31);
        if (c < 32)       m0 |= bit << (c & 31);
        else if (c < 64)  m1 |= bit << (c & 31);
        else if (c < 96)  m2 |= bit << (c & 31);
        else              m3 |= bit << (c & 31);
    }
    Wp[t] = make_uint4(m0, m1, m2, m3);
    cw[t] = CIN - 2 * (__popc(m0) + __popc(m1) + __popc(m2) + __popc(m3));
}

// each thread packs 4 consecutive pixels across all 128 channels (float4 loads)
__global__ __launch_bounds__(256) void pack_x_kernel(const float* __restrict__ x,
                                                     uint4* __restrict__ pkx) {
    int gid = blockIdx.x * blockDim.x + threadIdx.x;   // 0..100351
    int n = gid / (HW / 4);
    int p = (gid - n * (HW / 4)) * 4;
    const float* xp = x + (size_t)n * CIN * HW + p;
    uint32_t m[4][4] = {{0,0,0,0},{0,0,0,0},{0,0,0,0},{0,0,0,0}};
    #pragma unroll
    for (int c = 0; c < CIN; c++) {
        float4 v = *reinterpret_cast<const float4*>(xp + (size_t)c * HW);
        int q = c >> 5, s = c & 31;
        m[0][q] |= (__float_as_uint(v.x) >> 31) << s;
        m[1][q] |= (__float_as_uint(v.y) >> 31) << s;
        m[2][q] |= (__float_as_uint(v.z) >> 31) << s;
        m[3][q] |= (__float_as_uint(v.w) >> 31) << s;
    }
    uint4* op = pkx + (size_t)n * HW + p;
    #pragma unroll
    for (int j = 0; j < 4; j++)
        op[j] = make_uint4(m[j][0], m[j][1], m[j][2], m[j][3]);
}

// main conv: block = 16 co x 16 w-columns over a 16x16 pixel tile.
// Weights live in VGPRs (one co per thread); window streams from LDS
// with a sliding 3-row register window. OOB taps are zero bits,
// corrected by border_fix_kernel.
__global__ __launch_bounds__(256) void binconv_kernel(
    const uint4* __restrict__ pkx, const uint4* __restrict__ Wp,
    const float* __restrict__ bias, float* __restrict__ out) {
    __shared__ uint4 tile[18 * 18];

    int tx = threadIdx.x & 15;        // w-column within tile
    int ci = threadIdx.x >> 4;        // co within group (0..15)
    int w0 = blockIdx.x * 16;
    int h0 = blockIdx.y * 16;
    int bz = blockIdx.z;
    int n  = bz >> 3;
    int co = (bz & 7) * 16 + ci;

    const uint4* px = pkx + (size_t)n * HW;

    // cooperative stage of 18x18 window (zeros for out-of-image)
    for (int i = threadIdx.x; i < 324; i += 256) {
        int r = i / 18, c = i - r * 18;
        int hh = h0 - 1 + r, ww = w0 - 1 + c;
        bool valid = (hh >= 0) & (hh < Hdim) & (ww >= 0) & (ww < Wdim);
        uint4 val = make_uint4(0u, 0u, 0u, 0u);
        if (valid) val = px[hh * Wdim + ww];
        tile[i] = val;
    }

    // this thread's 9 weight words -> registers (one-time, L1-resident)
    uint4 wt[9];
    #pragma unroll
    for (int t = 0; t < 9; t++) wt[t] = Wp[co * 9 + t];

    __syncthreads();

    // prime sliding window: tile rows 0,1 at cols tx..tx+2
    // invariant: tile row R lives in win[R % 3]
    uint4 win[3][3];
    #pragma unroll
    for (int r = 0; r < 2; r++)
        #pragma unroll
        for (int c = 0; c < 3; c++)
            win[r][c] = tile[r * 18 + tx + c];

    int w = w0 + tx;
    float fb = 1152.0f + bias[co];
    float* op = out + (size_t)(n * COUT + co) * HW + (size_t)h0 * Wdim + w;

    #pragma unroll
    for (int hs = 0; hs < 16; hs++) {
        // load incoming bottom row (tile row hs+2)
        #pragma unroll
        for (int c = 0; c < 3; c++)
            win[(hs + 2) % 3][c] = tile[(hs + 2) * 18 + tx + c];

        int P0 = 0, P1 = 0, P2 = 0, P3 = 0;
        #pragma unroll
        for (int t = 0; t < 9; t++) {
            uint4 a  = win[(hs + t / 3) % 3][t % 3];
            uint4 ww4 = wt[t];
            P0 += __popc(a.x ^ ww4.x);
            P1 += __popc(a.y ^ ww4.y);
            P2 += __popc(a.z ^ ww4.z);
            P3 += __popc(a.w ^ ww4.w);
        }
        op[hs * Wdim] = fmaf(-2.0f, (float)(P0 + P1 + P2 + P3), fb);
    }
}

// subtract the spurious zero-pad contribution on the 444 border pixels/image
__global__ void border_fix_kernel(const int* __restrict__ cw, float* __restrict__ out) {
    const int BP = 444;
    int t = blockIdx.x * blockDim.x + threadIdx.x;
    int total = NB * COUT * BP;
    if (t >= total) return;
    int bp = t % BP;
    int rc = t / BP;
    int co = rc % COUT;
    int n  = rc / COUT;
    int h, w;
    if (bp < 112)      { h = 0;   w = bp; }
    else if (bp < 224) { h = 111; w = bp - 112; }
    else { int r = bp - 224; h = (r >> 1) + 1; w = (r & 1) ? 111 : 0; }
    const int* c9 = cw + co * 9;
    int corr = 0;
    #pragma unroll
    for (int ky = 0; ky < 3; ky++) {
        #pragma unroll
        for (int kx = 0; kx < 3; kx++) {
            int hh = h + ky - 1, ww = w + kx - 1;
            if ((hh < 0) | (hh >= Hdim) | (ww < 0) | (ww >= Wdim))
                corr += c9[ky * 3 + kx];
        }
    }
    size_t idx = ((size_t)(n * COUT + co) * HW) + (size_t)h * Wdim + w;
    out[idx] -= (float)corr;
}

extern "C" void kernel_launch(void* const* d_in, const int* in_sizes, int n_in,
                              void* d_out, int out_size, void* d_ws, size_t ws_size,
                              hipStream_t stream) {
    const float* x = (const float*)d_in[0];
    const float* W = (const float*)d_in[1];
    const float* b = (const float*)d_in[2];
    float* out = (float*)d_out;
    char* ws = (char*)d_ws;
    uint4* Wp  = (uint4*)ws;
    int*   cw  = (int*)(ws + 18432);
    uint4* pkx = (uint4*)(ws + 23040);

    pack_w_kernel<<<dim3((COUT * 9 + 255) / 256), dim3(256), 0, stream>>>(W, Wp, cw);
    pack_x_kernel<<<dim3(NB * HW / 4 / 256), dim3(256), 0, stream>>>(x, pkx);
    binconv_kernel<<<dim3(7, 7, NB * 8), dim3(256), 0, stream>>>(pkx, Wp, b, out);
    border_fix_kernel<<<dim3((NB * COUT * 444 + 255) / 256), dim3(256), 0, stream>>>(cw, out);
}